// Round 13
// baseline (244.823 us; speedup 1.0000x reference)
//
#include <hip/hip_runtime.h>
#include <hip/hip_bf16.h>
#include <cstddef>

// Problem constants (EmbeddingEngine_47029891891415)
#define S_ 4
#define N_ 65536
#define K_ 64
#define D_ 256
#define P_ 8192

typedef __bf16 bf16x8 __attribute__((ext_vector_type(8)));
typedef float  f32x4  __attribute__((ext_vector_type(4)));

// Pack W [S][K=64][D=256] fp32 -> bf16 MFMA fragments in ws.
// wpack[(((s*2 + t)*16 + c)*64 + lane)*8 + i] =
//     bf16(W[s][t*32 + 8*(lane>>4) + i][c*16 + (lane&15)])
__global__ __launch_bounds__(256) void pack_w_kernel(const float* __restrict__ W,
                                                     __bf16* __restrict__ wpack) {
    int tid  = blockIdx.x * 256 + threadIdx.x;   // 0..65535
    int i    =  tid        & 7;
    int lane = (tid >> 3)  & 63;
    int c    = (tid >> 9)  & 15;
    int t    = (tid >> 13) & 1;
    int s    =  tid >> 14;
    int k    = t * 32 + 8 * (lane >> 4) + i;
    int col  = c * 16 + (lane & 15);
    wpack[tid] = (__bf16)W[(s * K_ + k) * D_ + col];
}

// SPLIT-PHASE DIAGNOSTIC. FREP=1 == R10-equivalent (107us best, control).
// FREP=2: the FRONT half (token loads, cvt, MFMA, pe gathers, bias adds) runs
// twice — pass-0 results kept live via asm sinks (no DCE, rule #17), memory
// clobber forces full re-issue of all loads — while the LDS-transposed store
// epilogue runs ONCE. Delta vs control isolates the front-end marginal cost
// from the store-path cost. Both variants write identical values.
template<int FREP>
__global__ __launch_bounds__(256) void embed_tpl(
        const float* __restrict__ tokens,    // [S][N][K] f32
        const float* __restrict__ bvec,      // [S][D] f32
        const float* __restrict__ pe,        // [P][D] f32
        const int*   __restrict__ idxs,      // [S][N] i32
        const int*   __restrict__ idxs_pe,   // [S][N] i32
        const __bf16* __restrict__ wpack,    // packed W fragments (L2)
        float* __restrict__ out) {           // [S*N][D] f32
    const int blk   = blockIdx.x;            // 0..4095
    const int s     = blk >> 10;             // 1024 tiles per stream
    const int tile  = blk & 1023;
    const int wave  = threadIdx.x >> 6;
    const int lane  = threadIdx.x & 63;
    const int j     = lane & 15;             // token within wave tile
    const int g     = lane >> 4;
    const int rowbase = tile * 64 + wave * 16;
    const int trowi   = rowbase + j;         // token row within stream

    __shared__ float lds[4][16][136];        // per-wave [row][128+8 pad]
    float* const wl = &lds[wave][0][0];

    const int ipe = idxs_pe[s * N_ + trowi];
    const float* __restrict__ perow = pe + (size_t)ipe * D_ + g * 4;
    const float* __restrict__ brow  = bvec + s * D_ + g * 4;
    const bf16x8* wp0 = (const bf16x8*)wpack + (size_t)((s * 2 + 0) * 16) * 64;
    const bf16x8* wp1 = (const bf16x8*)wpack + (size_t)((s * 2 + 1) * 16) * 64;
    const float* trow = tokens + ((size_t)s * N_ + trowi) * K_;

    f32x4 o[16];
#pragma unroll
    for (int rep = 0; rep < FREP; ++rep) {
        // ---- token fragments (NT streaming loads)
        f32x4 t0lo = __builtin_nontemporal_load((const f32x4*)(trow +      8 * g));
        f32x4 t0hi = __builtin_nontemporal_load((const f32x4*)(trow +      8 * g + 4));
        f32x4 t1lo = __builtin_nontemporal_load((const f32x4*)(trow + 32 + 8 * g));
        f32x4 t1hi = __builtin_nontemporal_load((const f32x4*)(trow + 32 + 8 * g + 4));
        bf16x8 a0, a1;
#pragma unroll
        for (int e = 0; e < 4; ++e) {
            a0[e]     = (__bf16)t0lo[e];
            a0[e + 4] = (__bf16)t0hi[e];
            a1[e]     = (__bf16)t1lo[e];
            a1[e + 4] = (__bf16)t1hi[e];
        }
        // ---- full MFMA block (swapped operands; C/D m89/m91)
        f32x4 acc[16];
#pragma unroll
        for (int c = 0; c < 16; ++c) acc[c] = (f32x4){0.f, 0.f, 0.f, 0.f};
#pragma unroll
        for (int c = 0; c < 16; ++c) {
            bf16x8 w0 = wp0[c * 64 + lane];
            bf16x8 w1 = wp1[c * 64 + lane];
            acc[c] = __builtin_amdgcn_mfma_f32_16x16x32_bf16(w0, a0, acc[c], 0, 0, 0);
            acc[c] = __builtin_amdgcn_mfma_f32_16x16x32_bf16(w1, a1, acc[c], 0, 0, 0);
        }
        // ---- pe gathers + bias -> o
#pragma unroll
        for (int c = 0; c < 16; ++c) {
            f32x4 pev = *(const f32x4*)(perow + c * 16);
            f32x4 bbv = *(const f32x4*)(brow  + c * 16);
            o[c] = acc[c] + bbv + pev;
        }
        if (rep != FREP - 1) {
            // Keep pass-0 work live (no DCE) without storing it.
#pragma unroll
            for (int c = 0; c < 16; ++c)
                asm volatile("" :: "v"(o[c][0]), "v"(o[c][1]),
                                   "v"(o[c][2]), "v"(o[c][3]));
            asm volatile("" ::: "memory");   // force re-issue of all loads
        }
    }

    // ---- Store epilogue (ONCE): R10's 2-pass LDS transpose + NT bursts
    const int hi = lane >> 5;
    const int lo = lane & 31;
#pragma unroll
    for (int p = 0; p < 2; ++p) {
#pragma unroll
        for (int cc = 0; cc < 8; ++cc)
            *(f32x4*)(wl + j * 136 + cc * 16 + g * 4) = o[p * 8 + cc];
#pragma unroll
        for (int rr = 0; rr < 8; ++rr) {
            const int r      = rr * 2 + hi;
            const int orow_r = idxs[s * N_ + rowbase + r];
            f32x4 v = *(const f32x4*)(wl + r * 136 + lo * 4);
            __builtin_nontemporal_store(
                v, (f32x4*)(out + (size_t)orow_r * D_ + p * 128 + lo * 4));
        }
    }
}

extern "C" void kernel_launch(void* const* d_in, const int* in_sizes, int n_in,
                              void* d_out, int out_size, void* d_ws, size_t ws_size,
                              hipStream_t stream) {
    const float* tokens  = (const float*)d_in[0];
    const float* W       = (const float*)d_in[1];
    const float* bvec    = (const float*)d_in[2];
    const float* pe      = (const float*)d_in[3];
    const int*   idxs    = (const int*)d_in[4];
    const int*   idxs_pe = (const int*)d_in[5];
    float* out = (float*)d_out;
    __bf16* wpack = (__bf16*)d_ws;   // 128 KB

    pack_w_kernel<<<256, 256, 0, stream>>>(W, wpack);
    // Control: R10-equivalent (within-probe baseline re-validation)
    embed_tpl<1><<<S_ * (N_ / 64), 256, 0, stream>>>(tokens, bvec, pe, idxs, idxs_pe,
                                                     wpack, out);
    // Diagnostic: front x2, store x1 -> delta isolates front-end cost
    embed_tpl<2><<<S_ * (N_ / 64), 256, 0, stream>>>(tokens, bvec, pe, idxs, idxs_pe,
                                                     wpack, out);
}

// Round 14
// 124.576 us; speedup vs baseline: 1.9653x; 1.9653x over previous
//
#include <hip/hip_runtime.h>
#include <hip/hip_bf16.h>
#include <cstddef>

// Problem constants (EmbeddingEngine_47029891891415)
#define S_ 4
#define N_ 65536
#define K_ 64
#define D_ 256
#define P_ 8192

typedef __bf16 bf16x8 __attribute__((ext_vector_type(8)));
typedef float  f32x4  __attribute__((ext_vector_type(4)));

// Pack W [S][K=64][D=256] fp32 -> bf16 MFMA fragments in ws.
// wpack[(((s*2 + t)*16 + c)*64 + lane)*8 + i] =
//     bf16(W[s][t*32 + 8*(lane>>4) + i][c*16 + (lane&15)])
__global__ __launch_bounds__(256) void pack_w_kernel(const float* __restrict__ W,
                                                     __bf16* __restrict__ wpack) {
    int tid  = blockIdx.x * 256 + threadIdx.x;   // 0..65535
    int i    =  tid        & 7;
    int lane = (tid >> 3)  & 63;
    int c    = (tid >> 9)  & 15;
    int t    = (tid >> 13) & 1;
    int s    =  tid >> 14;
    int k    = t * 32 + 8 * (lane >> 4) + i;
    int col  = c * 16 + (lane & 15);
    wpack[tid] = (__bf16)W[(s * K_ + k) * D_ + col];
}

// R10 (107us best) + ONE lever: cross-tile software pipeline.
// Each block = 2 consecutive 64-token tiles. Tile1's token NT-loads are
// issued BEFORE tile0's MFMA/epilogue (T14 issue-early): HBM token latency
// and tile1's front hide under tile0's store bursts; tile0's epilogue
// latency chain (gather->ds_write->ds_read->store) overlaps tile1's
// independent front. R13 split-phase measured front marginal ~27us vs
// epilogue ~80us of 107 -> the wall is front/epilogue non-overlap.
// All R10-proven structure unchanged: 4 waves, LDS [16][136] 2-pass
// transposed epilogue, 512B contiguous NT bursts, swapped-operand MFMA
// (C/D m89/m91: col(lane&15)=token, row(g*4+reg)=d_local).
__global__ __launch_bounds__(256) void embed_kernel(
        const float* __restrict__ tokens,    // [S][N][K] f32
        const float* __restrict__ bvec,      // [S][D] f32
        const float* __restrict__ pe,        // [P][D] f32
        const int*   __restrict__ idxs,      // [S][N] i32
        const int*   __restrict__ idxs_pe,   // [S][N] i32
        const __bf16* __restrict__ wpack,    // packed W fragments (L2)
        float* __restrict__ out) {           // [S*N][D] f32
    const int blk   = blockIdx.x;            // 0..2047
    const int s     = blk >> 9;              // 512 tile-pairs per stream
    const int pair  = blk & 511;
    const int tile0 = pair * 2;
    const int wave  = threadIdx.x >> 6;
    const int lane  = threadIdx.x & 63;
    const int j     = lane & 15;             // token within wave tile
    const int g     = lane >> 4;
    const int rowbase0 = tile0 * 64 + wave * 16;   // tile0 rows
    const int trowi0   = rowbase0 + j;

    __shared__ float lds[4][16][136];        // per-wave [row][128+8 pad]
    float* const wl = &lds[wave][0][0];

    const bf16x8* wp0 = (const bf16x8*)wpack + (size_t)((s * 2 + 0) * 16) * 64;
    const bf16x8* wp1 = (const bf16x8*)wpack + (size_t)((s * 2 + 1) * 16) * 64;
    const float* __restrict__ brow = bvec + s * D_ + g * 4;
    const int hi = lane >> 5;
    const int lo = lane & 31;

    // ---- shared epilogue: MFMA + gather + LDS transpose + NT bursts
    auto do_tile = [&](bf16x8 a0, bf16x8 a1, int rowb, int ipe) {
        f32x4 acc[16];
#pragma unroll
        for (int c = 0; c < 16; ++c) acc[c] = (f32x4){0.f, 0.f, 0.f, 0.f};
#pragma unroll
        for (int c = 0; c < 16; ++c) {
            bf16x8 w0 = wp0[c * 64 + lane];
            bf16x8 w1 = wp1[c * 64 + lane];
            acc[c] = __builtin_amdgcn_mfma_f32_16x16x32_bf16(w0, a0, acc[c], 0, 0, 0);
            acc[c] = __builtin_amdgcn_mfma_f32_16x16x32_bf16(w1, a1, acc[c], 0, 0, 0);
        }
        const float* __restrict__ perow = pe + (size_t)ipe * D_ + g * 4;
#pragma unroll
        for (int p = 0; p < 2; ++p) {
#pragma unroll
            for (int cc = 0; cc < 8; ++cc) {
                const int c = p * 8 + cc;
                f32x4 pev = *(const f32x4*)(perow + c * 16);
                f32x4 bbv = *(const f32x4*)(brow  + c * 16);
                f32x4 o   = acc[c] + bbv + pev;
                *(f32x4*)(wl + j * 136 + cc * 16 + g * 4) = o;
            }
#pragma unroll
            for (int rr = 0; rr < 8; ++rr) {
                const int r      = rr * 2 + hi;
                const int orow_r = idxs[s * N_ + rowb + r];
                f32x4 v = *(const f32x4*)(wl + r * 136 + lo * 4);
                __builtin_nontemporal_store(
                    v, (f32x4*)(out + (size_t)orow_r * D_ + p * 128 + lo * 4));
            }
        }
    };

    // ---- prologue: tile0 tokens + both pe indices
    const float* trow0 = tokens + ((size_t)s * N_ + trowi0) * K_;
    const float* trow1 = trow0 + 64 * K_;    // tile1, same wave/j
    f32x4 p0a = __builtin_nontemporal_load((const f32x4*)(trow0 +      8 * g));
    f32x4 p0b = __builtin_nontemporal_load((const f32x4*)(trow0 +      8 * g + 4));
    f32x4 p0c = __builtin_nontemporal_load((const f32x4*)(trow0 + 32 + 8 * g));
    f32x4 p0d = __builtin_nontemporal_load((const f32x4*)(trow0 + 32 + 8 * g + 4));
    const int ipe0 = idxs_pe[s * N_ + trowi0];
    const int ipe1 = idxs_pe[s * N_ + trowi0 + 64];

    // ---- tile0 cvt
    bf16x8 a0, a1;
#pragma unroll
    for (int e = 0; e < 4; ++e) {
        a0[e]     = (__bf16)p0a[e];
        a0[e + 4] = (__bf16)p0b[e];
        a1[e]     = (__bf16)p0c[e];
        a1[e + 4] = (__bf16)p0d[e];
    }

    // ---- ISSUE tile1 token loads now (hide under tile0 MFMA+epilogue)
    f32x4 p1a = __builtin_nontemporal_load((const f32x4*)(trow1 +      8 * g));
    f32x4 p1b = __builtin_nontemporal_load((const f32x4*)(trow1 +      8 * g + 4));
    f32x4 p1c = __builtin_nontemporal_load((const f32x4*)(trow1 + 32 + 8 * g));
    f32x4 p1d = __builtin_nontemporal_load((const f32x4*)(trow1 + 32 + 8 * g + 4));

    // ---- tile0 compute + store
    do_tile(a0, a1, rowbase0, ipe0);

    // ---- tile1 cvt + compute + store
    bf16x8 b0, b1;
#pragma unroll
    for (int e = 0; e < 4; ++e) {
        b0[e]     = (__bf16)p1a[e];
        b0[e + 4] = (__bf16)p1b[e];
        b1[e]     = (__bf16)p1c[e];
        b1[e + 4] = (__bf16)p1d[e];
    }
    do_tile(b0, b1, rowbase0 + 64, ipe1);
}

extern "C" void kernel_launch(void* const* d_in, const int* in_sizes, int n_in,
                              void* d_out, int out_size, void* d_ws, size_t ws_size,
                              hipStream_t stream) {
    const float* tokens  = (const float*)d_in[0];
    const float* W       = (const float*)d_in[1];
    const float* bvec    = (const float*)d_in[2];
    const float* pe      = (const float*)d_in[3];
    const int*   idxs    = (const int*)d_in[4];
    const int*   idxs_pe = (const int*)d_in[5];
    float* out = (float*)d_out;
    __bf16* wpack = (__bf16*)d_ws;   // 128 KB

    pack_w_kernel<<<256, 256, 0, stream>>>(W, wpack);
    embed_kernel<<<S_ * (N_ / 64) / 2, 256, 0, stream>>>(tokens, bvec, pe, idxs, idxs_pe,
                                                         wpack, out);
}

// Round 15
// 109.792 us; speedup vs baseline: 2.2299x; 1.1346x over previous
//
#include <hip/hip_runtime.h>
#include <hip/hip_bf16.h>
#include <cstddef>

// Problem constants (EmbeddingEngine_47029891891415)
#define S_ 4
#define N_ 65536
#define K_ 64
#define D_ 256
#define P_ 8192

typedef __bf16 bf16x8 __attribute__((ext_vector_type(8)));
typedef float  f32x4  __attribute__((ext_vector_type(4)));

// Pack W [S][K=64][D=256] fp32 -> bf16 MFMA fragments in ws.
// wpack[(((s*2 + t)*16 + c)*64 + lane)*8 + i] =
//     bf16(W[s][t*32 + 8*(lane>>4) + i][c*16 + (lane&15)])
__global__ __launch_bounds__(256) void pack_w_kernel(const float* __restrict__ W,
                                                     __bf16* __restrict__ wpack) {
    int tid  = blockIdx.x * 256 + threadIdx.x;   // 0..65535
    int i    =  tid        & 7;
    int lane = (tid >> 3)  & 63;
    int c    = (tid >> 9)  & 15;
    int t    = (tid >> 13) & 1;
    int s    =  tid >> 14;
    int k    = t * 32 + 8 * (lane >> 4) + i;
    int col  = c * 16 + (lane & 15);
    wpack[tid] = (__bf16)W[(s * K_ + k) * D_ + col];
}

// R10 (107us best) with EXACTLY ONE lever changed: the 512B-contiguous
// burst stores are PLAIN instead of nontemporal. Mechanism under test:
// plain stores write-allocate and line-merge in L2, writing back full
// lines (the fillBuffer pattern, 6.9 TB/s on this box); NT streams past
// L2 and may pay sector-granular write amplification (R6 measured 1.33x
// with NT direct stores). The earlier plain-store loss (R5: 147us) was on
// the DIRECT epilogue with a register-spill confound — this is the clean
// test on the transposed epilogue. Everything else byte-identical to R10:
// 4096 blocks, 4 waves, NT token loads, swapped-operand MFMA (C/D m89/m91:
// col(lane&15)=token, row(g*4+reg)=d_local), LDS [16][136] 2-pass
// transpose, 16 burst stores of 2 rows x 512B each.
__global__ __launch_bounds__(256) void embed_kernel(
        const float* __restrict__ tokens,    // [S][N][K] f32
        const float* __restrict__ bvec,      // [S][D] f32
        const float* __restrict__ pe,        // [P][D] f32
        const int*   __restrict__ idxs,      // [S][N] i32
        const int*   __restrict__ idxs_pe,   // [S][N] i32
        const __bf16* __restrict__ wpack,    // packed W fragments (L2)
        float* __restrict__ out) {           // [S*N][D] f32
    const int blk   = blockIdx.x;            // 0..4095
    const int s     = blk >> 10;             // 1024 tiles per stream
    const int tile  = blk & 1023;
    const int wave  = threadIdx.x >> 6;
    const int lane  = threadIdx.x & 63;
    const int j     = lane & 15;             // token within wave tile
    const int g     = lane >> 4;
    const int rowbase = tile * 64 + wave * 16;
    const int trowi   = rowbase + j;         // token row within stream

    __shared__ float lds[4][16][136];        // per-wave [row][128+8 pad]
    float* const wl = &lds[wave][0][0];

    // ---- token fragments: tok[trowi][k], k = t*32 + 8g + e (streaming)
    const float* trow = tokens + ((size_t)s * N_ + trowi) * K_;
    f32x4 t0lo = __builtin_nontemporal_load((const f32x4*)(trow +      8 * g));
    f32x4 t0hi = __builtin_nontemporal_load((const f32x4*)(trow +      8 * g + 4));
    f32x4 t1lo = __builtin_nontemporal_load((const f32x4*)(trow + 32 + 8 * g));
    f32x4 t1hi = __builtin_nontemporal_load((const f32x4*)(trow + 32 + 8 * g + 4));
    bf16x8 a0, a1;
#pragma unroll
    for (int e = 0; e < 4; ++e) {
        a0[e]     = (__bf16)t0lo[e];
        a0[e + 4] = (__bf16)t0hi[e];
        a1[e]     = (__bf16)t1lo[e];
        a1[e + 4] = (__bf16)t1hi[e];
    }

    // ---- W fragments (L2-resident) + MFMA (swapped operands)
    const bf16x8* wp0 = (const bf16x8*)wpack + (size_t)((s * 2 + 0) * 16) * 64;
    const bf16x8* wp1 = (const bf16x8*)wpack + (size_t)((s * 2 + 1) * 16) * 64;

    f32x4 acc[16];
#pragma unroll
    for (int c = 0; c < 16; ++c) acc[c] = (f32x4){0.f, 0.f, 0.f, 0.f};
#pragma unroll
    for (int c = 0; c < 16; ++c) {
        bf16x8 w0 = wp0[c * 64 + lane];
        bf16x8 w1 = wp1[c * 64 + lane];
        acc[c] = __builtin_amdgcn_mfma_f32_16x16x32_bf16(w0, a0, acc[c], 0, 0, 0);
        acc[c] = __builtin_amdgcn_mfma_f32_16x16x32_bf16(w1, a1, acc[c], 0, 0, 0);
    }

    // ---- Epilogue
    const int ipe  = idxs_pe[s * N_ + trowi];
    const float* __restrict__ perow = pe + (size_t)ipe * D_ + g * 4;
    const float* __restrict__ brow  = bvec + s * D_ + g * 4;
    const int   hi = lane >> 5;              // row parity for store phase
    const int   lo = lane & 31;              // 32-lane half-row cover

#pragma unroll
    for (int p = 0; p < 2; ++p) {
        // Phase 1: gather pe + bias, stage fragment into LDS (wave-private)
#pragma unroll
        for (int cc = 0; cc < 8; ++cc) {
            const int c = p * 8 + cc;
            f32x4 pev = *(const f32x4*)(perow + c * 16);
            f32x4 bbv = *(const f32x4*)(brow  + c * 16);
            f32x4 o   = acc[c] + bbv + pev;
            *(f32x4*)(wl + j * 136 + cc * 16 + g * 4) = o;
        }
        // Phase 2: contiguous store burst — 2 rows x 512B per instr, PLAIN
#pragma unroll
        for (int rr = 0; rr < 8; ++rr) {
            const int r      = rr * 2 + hi;
            const int orow_r = idxs[s * N_ + rowbase + r];
            f32x4 v = *(const f32x4*)(wl + r * 136 + lo * 4);
            *(f32x4*)(out + (size_t)orow_r * D_ + p * 128 + lo * 4) = v;
        }
    }
}

extern "C" void kernel_launch(void* const* d_in, const int* in_sizes, int n_in,
                              void* d_out, int out_size, void* d_ws, size_t ws_size,
                              hipStream_t stream) {
    const float* tokens  = (const float*)d_in[0];
    const float* W       = (const float*)d_in[1];
    const float* bvec    = (const float*)d_in[2];
    const float* pe      = (const float*)d_in[3];
    const int*   idxs    = (const int*)d_in[4];
    const int*   idxs_pe = (const int*)d_in[5];
    float* out = (float*)d_out;
    __bf16* wpack = (__bf16*)d_ws;   // 128 KB

    pack_w_kernel<<<256, 256, 0, stream>>>(W, wpack);
    embed_kernel<<<S_ * (N_ / 64), 256, 0, stream>>>(tokens, bvec, pe, idxs, idxs_pe,
                                                     wpack, out);
}